// Round 17
// baseline (480.643 us; speedup 1.0000x reference)
//
#include <hip/hip_runtime.h>

#define N_NODES 100000
#define N_EDGES 1600000
#define D_IN 128
#define HID 64
#define N_LAYERS 5
#define D_OUT 32
#define N_GRAPHS 1000

// bucketed CSR build
#define BSHIFT 7                          // 128 nodes per bucket
#define NBUCK ((N_NODES + 127) >> BSHIFT) // 782
#define CNT_B 256                         // blocks in count/scatter passes
#define EPB (N_EDGES / CNT_B)             // 6250 edges per block slice
#define NT (NBUCK * CNT_B)                // table entries = 200192

typedef unsigned short ushort_t;
typedef unsigned int uint_t;
typedef __attribute__((ext_vector_type(8))) short short8;   // 8 bf16 (4 VGPRs)
typedef __attribute__((ext_vector_type(4))) float f32x4;    // MFMA accumulator

#define MFMA(a, b, c) __builtin_amdgcn_mfma_f32_16x16x32_bf16((a), (b), (c), 0, 0, 0)

// per-layer stride of the prepped GRU weight fragment arrays (in shorts)
#define WSTRIDE (24 * 2 * 64 * 8)
#define NW (N_LAYERS * WSTRIDE)          // 122880
#define WIN_N (4 * 4 * 64 * 8)           // W_in fragments per plane = 8192

#define IN_B ((N_NODES + 63) / 64)       // 1563 input-MFMA blocks
#define CTOT (CNT_B + IN_B)              // 1819 (coprime with 256)

__device__ __forceinline__ float fast_sigmoid(float x) {
    return __builtin_amdgcn_rcpf(1.0f + __expf(-x));
}
__device__ __forceinline__ float fast_tanh(float x) {
    return 1.0f - 2.0f * __builtin_amdgcn_rcpf(1.0f + __expf(2.0f * x));
}
// fp32 -> bf16 round-to-nearest-even
__device__ __forceinline__ ushort_t f2bf(float f) {
    uint_t u = __float_as_uint(f);
    return (ushort_t)((u + 0x7fffu + ((u >> 16) & 1u)) >> 16);
}
__device__ __forceinline__ float b2f(ushort_t u) {
    return __uint_as_float(((uint_t)u) << 16);
}
// load 8 consecutive floats, split each into bf16 hi + bf16 lo
__device__ __forceinline__ void split8(const float* p, short8& hi, short8& lo) {
    float4 u0 = *(const float4*)p;
    float4 u1 = *(const float4*)(p + 4);
#define SPL(ii, fv) { float f_ = (fv); ushort_t h_ = f2bf(f_); hi[ii] = (short)h_;          \
                      float r_ = f_ - __uint_as_float(((uint_t)h_) << 16); lo[ii] = (short)f2bf(r_); }
    SPL(0, u0.x) SPL(1, u0.y) SPL(2, u0.z) SPL(3, u0.w)
    SPL(4, u1.x) SPL(5, u1.y) SPL(6, u1.z) SPL(7, u1.w)
#undef SPL
}

// ---------------------------------------------------------------------------
// Weight prep: GRU fragments (t < NW) and W_in fragments (t >= NW).
// Also zeroes sums/cnt and the tscan done-counter.
__global__ void k_prep(const float* __restrict__ ggnn_w,
                       const float* __restrict__ w_ih,
                       const float* __restrict__ w_hh,
                       const float* __restrict__ W_in,
                       short* __restrict__ Whi, short* __restrict__ Wlo,
                       short* __restrict__ WinHi, short* __restrict__ WinLo,
                       float* __restrict__ sums, int* __restrict__ done) {
    int t = blockIdx.x * blockDim.x + threadIdx.x;
    if (t == 0) *done = 0;
    if (t < N_GRAPHS * (HID + 1)) sums[t] = 0.0f;
    if (t < NW) {
        int i    = t & 7;
        int lane = (t >> 3) & 63;
        int s    = (t >> 9) & 1;
        int tt   = (t >> 10) % 24;
        int lay  = (t >> 10) / 24;
        int k    = s * 32 + (lane >> 4) * 8 + i;
        int col  = tt * 16 + (lane & 15);
        float val;
        if (col < 192) {
            const float* wl = ggnn_w + ((size_t)lay * HID + k) * HID;
            const float* wi = w_ih + (size_t)col * HID;
            float acc = 0.0f;
#pragma unroll 8
            for (int q = 0; q < HID; ++q) acc = fmaf(wl[q], wi[q], acc);
            val = acc;
        } else {
            val = w_hh[(size_t)(col - 192) * HID + k];
        }
        ushort_t h_ = f2bf(val);
        Whi[t] = (short)h_;
        Wlo[t] = (short)f2bf(val - b2f(h_));
        return;
    }
    int t2 = t - NW;
    if (t2 >= WIN_N) return;
    int i    = t2 & 7;
    int lane = (t2 >> 3) & 63;
    int jb   = (t2 >> 9) & 3;
    int s    = (t2 >> 11) & 3;
    int k    = s * 32 + (lane >> 4) * 8 + i;
    int col  = jb * 16 + (lane & 15);
    float val = W_in[(size_t)k * HID + col];
    ushort_t h_ = f2bf(val);
    WinHi[t2] = (short)h_;
    WinLo[t2] = (short)f2bf(val - b2f(h_));
}

// ---------------------------------------------------------------------------
// count + input-MFMA, role-interleaved via bijective permutation
__global__ __launch_bounds__(256) void k_cntin(
        const int* __restrict__ ei, int* __restrict__ table,
        const float* __restrict__ ne,
        const short* __restrict__ WinHi, const short* __restrict__ WinLo,
        const float* __restrict__ b_in,
        ushort_t* __restrict__ h0) {
    __shared__ int hcnt[NBUCK];
    int tid = threadIdx.x;
    int swz = (int)(((long long)blockIdx.x * 256) % CTOT);

    if (swz < CNT_B) {
        int b = swz;
        for (int i = tid; i < NBUCK; i += 256) hcnt[i] = 0;
        __syncthreads();
        int e0 = b * EPB;
        for (int i = tid; i < EPB; i += 256)
            atomicAdd(&hcnt[ei[N_EDGES + e0 + i] >> BSHIFT], 1);
        __syncthreads();
        for (int i = tid; i < NBUCK; i += 256)
            table[i * CNT_B + b] = hcnt[i];
        return;
    }
    // ---- input linear via MFMA: x = ne @ W_in + b_in -> bf16 h0 ----
    int ib = swz - CNT_B;
    int wv = tid >> 6, l = tid & 63;
    int q = l >> 4, c = l & 15;
    int nodeBase = ib * 64 + wv * 16;
    int anode = nodeBase + c;
    int acl = (anode < N_NODES) ? anode : (N_NODES - 1);
    const float* erow = ne + (size_t)acl * D_IN;
    short8 Ah[4], Al[4];
#pragma unroll
    for (int s = 0; s < 4; ++s) split8(erow + s * 32 + q * 8, Ah[s], Al[s]);

    f32x4 acc[4];
    const f32x4 zero = {0.f, 0.f, 0.f, 0.f};
#pragma unroll
    for (int jb = 0; jb < 4; ++jb) acc[jb] = zero;
    const short8* BH = ((const short8*)WinHi) + l;
    const short8* BL = ((const short8*)WinLo) + l;
#pragma unroll
    for (int jb = 0; jb < 4; ++jb)
#pragma unroll
        for (int s = 0; s < 4; ++s) {
            short8 bh = BH[(s * 4 + jb) * 64];
            short8 bl = BL[(s * 4 + jb) * 64];
            acc[jb] = MFMA(Ah[s], bh, acc[jb]);
            acc[jb] = MFMA(Al[s], bh, acc[jb]);
            acc[jb] = MFMA(Ah[s], bl, acc[jb]);
        }
#pragma unroll
    for (int jb = 0; jb < 4; ++jb) {
        int j = jb * 16 + c;
        float bb = b_in[j];
#pragma unroll
        for (int i = 0; i < 4; ++i) {
            int m = nodeBase + q * 4 + i;
            if (m < N_NODES)
                h0[(size_t)m * HID + j] = f2bf(acc[jb][i] + bb);
        }
    }
}

// ---------------------------------------------------------------------------
// Flat exclusive scan over NT entries; LAST BLOCK scans the chunk sums.
#define SCHUNK 1024
__global__ __launch_bounds__(1024) void k_tscan1(int* __restrict__ table,
                                                 int* __restrict__ bsum,
                                                 int* __restrict__ done) {
    __shared__ int buf[SCHUNK];
    __shared__ int lastFlag;
    int tid = threadIdx.x;
    int i = blockIdx.x * SCHUNK + tid;
    int v = (i < NT) ? table[i] : 0;
    buf[tid] = v;
    __syncthreads();
    for (int s = 1; s < SCHUNK; s <<= 1) {
        int a = (tid >= s) ? buf[tid - s] : 0;
        __syncthreads();
        buf[tid] += a;
        __syncthreads();
    }
    if (i < NT) table[i] = buf[tid] - v;    // exclusive within chunk
    if (tid == SCHUNK - 1) atomicExch(&bsum[blockIdx.x], buf[tid]);
    if (tid == 0) {
        __threadfence();
        lastFlag = (atomicAdd(done, 1) == (int)gridDim.x - 1) ? 1 : 0;
    }
    __syncthreads();
    if (!lastFlag) return;
    int nch = gridDim.x;
    int bv = (tid < nch) ? atomicAdd(&bsum[tid], 0) : 0;   // coherent read
    buf[tid] = bv;
    __syncthreads();
    for (int s = 1; s < SCHUNK; s <<= 1) {
        int a = (tid >= s) ? buf[tid - s] : 0;
        __syncthreads();
        buf[tid] += a;
        __syncthreads();
    }
    if (tid < nch) atomicExch(&bsum[tid], buf[tid] - bv);
}

// ---------------------------------------------------------------------------
// LDS counting-sort scatter; global eb entries packed: src | ((dst&127)<<17)
__global__ __launch_bounds__(256) void k_scatter(const int* __restrict__ ei,
                                                 const int* __restrict__ table,
                                                 const int* __restrict__ bsum,
                                                 uint_t* __restrict__ eb) {
    __shared__ uint2 stage[EPB];        // 50,000 B
    __shared__ int hoff[NBUCK];
    __shared__ int hslot[NBUCK];
    __shared__ int sbuf[256];
    int b = blockIdx.x, tid = threadIdx.x;
    for (int i = tid; i < NBUCK; i += 256) { hoff[i] = 0; hslot[i] = 0; }
    __syncthreads();
    int e0 = b * EPB;
    for (int i = tid; i < EPB; i += 256)
        atomicAdd(&hoff[ei[N_EDGES + e0 + i] >> BSHIFT], 1);
    __syncthreads();
    int base = tid * 4;
    int c0 = (base + 0 < NBUCK) ? hoff[base + 0] : 0;
    int c1 = (base + 1 < NBUCK) ? hoff[base + 1] : 0;
    int c2 = (base + 2 < NBUCK) ? hoff[base + 2] : 0;
    int c3 = (base + 3 < NBUCK) ? hoff[base + 3] : 0;
    int tot = c0 + c1 + c2 + c3;
    sbuf[tid] = tot;
    __syncthreads();
    for (int s = 1; s < 256; s <<= 1) {
        int a = (tid >= s) ? sbuf[tid - s] : 0;
        __syncthreads();
        sbuf[tid] += a;
        __syncthreads();
    }
    int mybase = sbuf[tid] - tot;
    __syncthreads();
    if (base + 0 < NBUCK) hoff[base + 0] = mybase;
    if (base + 1 < NBUCK) hoff[base + 1] = mybase + c0;
    if (base + 2 < NBUCK) hoff[base + 2] = mybase + c0 + c1;
    if (base + 3 < NBUCK) hoff[base + 3] = mybase + c0 + c1 + c2;
    __syncthreads();
    for (int i = tid; i < EPB; i += 256) {
        int s = ei[e0 + i];
        int d = ei[N_EDGES + e0 + i];
        int bk = d >> BSHIFT;
        int pos = hoff[bk] + atomicAdd(&hslot[bk], 1);
        uint2 v; v.x = (uint_t)s; v.y = (uint_t)d;
        stage[pos] = v;
    }
    __syncthreads();
    for (int p = tid; p < EPB; p += 256) {
        uint2 e = stage[p];
        int bk = (int)e.y >> BSHIFT;
        int gidx = bk * CNT_B + b;
        int gbase = table[gidx] + bsum[gidx >> 10];
        eb[gbase + (p - hoff[bk])] = e.x | ((e.y & 127u) << 17);
    }
}

// ---------------------------------------------------------------------------
// per-bucket local CSR build (packed eb: src = e&0x1FFFF, dst-local = e>>17)
__global__ __launch_bounds__(256) void k_csr(const int* __restrict__ table,
                                             const int* __restrict__ bsum,
                                             const uint_t* __restrict__ eb,
                                             int* __restrict__ csr,
                                             int* __restrict__ off) {
    __shared__ int cnt[128];
    __shared__ int slot[128];
    int b = blockIdx.x, tid = threadIdx.x;
    int nodeBase = b << BSHIFT;
    int nn = min(128, N_NODES - nodeBase);
    int i0 = b * CNT_B;
    int beg = table[i0] + bsum[i0 >> 10];
    int end;
    if (b == NBUCK - 1) end = N_EDGES;
    else {
        int i1 = (b + 1) * CNT_B;
        end = table[i1] + bsum[i1 >> 10];
    }

    if (tid < 128) { cnt[tid] = 0; slot[tid] = 0; }
    __syncthreads();
    for (int i = beg + tid; i < end; i += 256)
        atomicAdd(&cnt[(eb[i] >> 17) & 127u], 1);
    __syncthreads();
    int orig = (tid < 128) ? cnt[tid] : 0;
    for (int s = 1; s < 128; s <<= 1) {
        int a = (tid >= s && tid < 128) ? cnt[tid - s] : 0;
        __syncthreads();
        if (tid < 128) cnt[tid] += a;
        __syncthreads();
    }
    int start = 0;
    if (tid < 128) start = beg + cnt[tid] - orig;
    __syncthreads();
    if (tid < 128) {
        cnt[tid] = start;
        if (tid < nn) off[nodeBase + tid] = start;
    }
    if (b == NBUCK - 1 && tid == 0) off[N_NODES] = N_EDGES;
    __syncthreads();
    for (int i = beg + tid; i < end; i += 256) {
        uint_t e = eb[i];
        int ln = (e >> 17) & 127u;
        int p = cnt[ln] + atomicAdd(&slot[ln], 1);
        csr[p] = (int)(e & 0x1FFFFu);
    }
}

// ---------------------------------------------------------------------------
// Fused layer: each WAVE owns a 16-node tile. It gathers the tile's neighbor
// sums into a wave-private LDS patch (no barriers; same-wave LDS ops are
// ordered), then runs the MFMA GRU on its tile. Reads h_old only, writes
// h_new rows it exclusively owns -> no races; ping-pong buffers per layer.
__global__ __launch_bounds__(256) void k_layer(
        const int* __restrict__ off, const int* __restrict__ csr,
        const ushort_t* __restrict__ hold_, ushort_t* __restrict__ hnew,
        const short* __restrict__ Whi, const short* __restrict__ Wlo,
        const float* __restrict__ b_ih, const float* __restrict__ b_hh) {
    __shared__ ushort_t sA[4][16][64];         // 8 KB, wave-private quarters
    int tid = threadIdx.x;
    int wv = tid >> 6, lane = tid & 63;
    int nodeBase = blockIdx.x * 64 + wv * 16;

    // ---- gather phase: 16 nodes, 8 neighbor rows in flight each ----
    {
        int q = lane >> 3, c = lane & 7;
        for (int m = 0; m < 16; ++m) {
            int n = nodeBase + m;                    // wave-uniform
            if (n >= N_NODES) break;
            int beg = off[n], end = off[n + 1];
            float a[8];
#pragma unroll
            for (int x = 0; x < 8; ++x) a[x] = 0.f;
#pragma unroll 2
            for (int i = beg; i < end; i += 8) {
                int idx = i + q;
                int sidx = csr[min(idx, end - 1)];
                float msk = (idx < end) ? 1.0f : 0.0f;
                uint4 v = *(const uint4*)(hold_ + (size_t)sidx * HID + c * 8);
                a[0] = fmaf(msk, __uint_as_float(v.x << 16), a[0]);
                a[1] = fmaf(msk, __uint_as_float(v.x & 0xffff0000u), a[1]);
                a[2] = fmaf(msk, __uint_as_float(v.y << 16), a[2]);
                a[3] = fmaf(msk, __uint_as_float(v.y & 0xffff0000u), a[3]);
                a[4] = fmaf(msk, __uint_as_float(v.z << 16), a[4]);
                a[5] = fmaf(msk, __uint_as_float(v.z & 0xffff0000u), a[5]);
                a[6] = fmaf(msk, __uint_as_float(v.w << 16), a[6]);
                a[7] = fmaf(msk, __uint_as_float(v.w & 0xffff0000u), a[7]);
            }
#pragma unroll
            for (int x = 0; x < 8; ++x) {
                a[x] += __shfl_xor(a[x], 8);
                a[x] += __shfl_xor(a[x], 16);
                a[x] += __shfl_xor(a[x], 32);
            }
            if (q == 0) {
                uint4 o;
                o.x = (uint_t)f2bf(a[0]) | ((uint_t)f2bf(a[1]) << 16);
                o.y = (uint_t)f2bf(a[2]) | ((uint_t)f2bf(a[3]) << 16);
                o.z = (uint_t)f2bf(a[4]) | ((uint_t)f2bf(a[5]) << 16);
                o.w = (uint_t)f2bf(a[6]) | ((uint_t)f2bf(a[7]) << 16);
                *(uint4*)&sA[wv][m][c * 8] = o;
            }
        }
    }

    // ---- GRU phase on this wave's tile (reads sA, wave-local) ----
    int q = lane >> 4, c = lane & 15;
    int anode = nodeBase + c;
    int acl = (anode < N_NODES) ? anode : (N_NODES - 1);
    const ushort_t* hrow = hold_ + (size_t)acl * HID;
    short8 Ag[2], Ah[2];
    Ag[0] = *(const short8*)&sA[wv][c][q * 8];
    Ag[1] = *(const short8*)&sA[wv][c][32 + q * 8];
    Ah[0] = *(const short8*)(hrow + q * 8);
    Ah[1] = *(const short8*)(hrow + 32 + q * 8);

    const short8* BH = ((const short8*)Whi) + lane;
    const short8* BL = ((const short8*)Wlo) + lane;
    const f32x4 zero = {0.f, 0.f, 0.f, 0.f};

#pragma unroll
    for (int jb = 0; jb < 4; ++jb) {
        f32x4 acc6[6];
#pragma unroll
        for (int g = 0; g < 6; ++g) acc6[g] = zero;
#pragma unroll
        for (int g = 0; g < 6; ++g) {
            int t = g * 4 + jb;
            short8 b0h = BH[(t * 2 + 0) * 64];
            short8 b1h = BH[(t * 2 + 1) * 64];
            short8 a0 = (g < 3) ? Ag[0] : Ah[0];
            short8 a1 = (g < 3) ? Ag[1] : Ah[1];
            acc6[g] = MFMA(a0, b0h, acc6[g]);
            acc6[g] = MFMA(a1, b1h, acc6[g]);
            if (g == 2 || g == 5) {          // tanh path keeps lo-residual
                short8 b0l = BL[(t * 2 + 0) * 64];
                short8 b1l = BL[(t * 2 + 1) * 64];
                acc6[g] = MFMA(a0, b0l, acc6[g]);
                acc6[g] = MFMA(a1, b1l, acc6[g]);
            }
        }
        int j = jb * 16 + c;
        float br  = b_ih[j] + b_hh[j];
        float bz  = b_ih[64 + j] + b_hh[64 + j];
        float bin = b_ih[128 + j];
        float bhn = b_hh[128 + j];
#pragma unroll
        for (int i = 0; i < 4; ++i) {
            int m = nodeBase + q * 4 + i;
            if (m < N_NODES) {
                float rr = fast_sigmoid(acc6[0][i] + acc6[3][i] + br);
                float zz = fast_sigmoid(acc6[1][i] + acc6[4][i] + bz);
                float nv = fast_tanh((acc6[2][i] + bin) + rr * (acc6[5][i] + bhn));
                size_t idx = (size_t)m * HID + j;
                float hov = b2f(hold_[idx]);
                hnew[idx] = f2bf((1.0f - zz) * nv + zz * hov);
            }
        }
    }
}

// ---------------------------------------------------------------------------
#define POOL_NPW 32
__global__ void k_pool(const ushort_t* __restrict__ hb,
                       const int* __restrict__ batch,
                       float* __restrict__ sums,
                       float* __restrict__ cntf) {
    int wid = (blockIdx.x * blockDim.x + threadIdx.x) >> 6;
    int j = threadIdx.x & 63;
    int base = wid * POOL_NPW;
    if (base >= N_NODES) return;
    int end = base + POOL_NPW;
    if (end > N_NODES) end = N_NODES;
    float acc = 0.f, c = 0.f;
    int curg = batch[base];
    for (int n = base; n < end; ++n) {
        int g = batch[n];
        if (g != curg) {
            atomicAdd(&sums[(size_t)curg * HID + j], acc);
            if (j == 0) atomicAdd(&cntf[curg], c);
            acc = 0.f; c = 0.f; curg = g;
        }
        acc += b2f(hb[(size_t)n * HID + j]);
        c += 1.f;
    }
    atomicAdd(&sums[(size_t)curg * HID + j], acc);
    if (j == 0) atomicAdd(&cntf[curg], c);
}

__global__ void k_out(const float* __restrict__ sums,
                      const float* __restrict__ cntf,
                      const float* __restrict__ W_out,
                      const float* __restrict__ b_out,
                      float* __restrict__ out) {
    int t = blockIdx.x * blockDim.x + threadIdx.x;
    if (t >= N_GRAPHS * D_OUT) return;
    int g = t / D_OUT, o = t % D_OUT;
    float inv_c = __builtin_amdgcn_rcpf(fmaxf(cntf[g], 1.0f));
    float acc = 0.0f;
#pragma unroll
    for (int k = 0; k < HID; ++k)
        acc = fmaf(sums[g * HID + k], W_out[k * D_OUT + o], acc);
    out[t] = acc * inv_c + b_out[o];
}

// ---------------------------------------------------------------------------
static inline char* align256(char* p) {
    return (char*)(((uintptr_t)p + 255) & ~(uintptr_t)255);
}

extern "C" void kernel_launch(void* const* d_in, const int* in_sizes, int n_in,
                              void* d_out, int out_size, void* d_ws, size_t ws_size,
                              hipStream_t stream) {
    const float* node_embed = (const float*)d_in[0];
    const int*   edge_index = (const int*)  d_in[1];
    const int*   batch      = (const int*)  d_in[2];
    const float* W_in       = (const float*)d_in[3];
    const float* b_in       = (const float*)d_in[4];
    const float* ggnn_w     = (const float*)d_in[5];
    const float* gru_w_ih   = (const float*)d_in[6];
    const float* gru_w_hh   = (const float*)d_in[7];
    const float* gru_b_ih   = (const float*)d_in[8];
    const float* gru_b_hh   = (const float*)d_in[9];
    const float* W_out      = (const float*)d_in[10];
    const float* b_out      = (const float*)d_in[11];
    float* out = (float*)d_out;

    char* p = (char*)d_ws;
    ushort_t* h0    = (ushort_t*)p; p = align256(p + (size_t)N_NODES * HID * sizeof(ushort_t));
    ushort_t* h1    = (ushort_t*)p; p = align256(p + (size_t)N_NODES * HID * sizeof(ushort_t));
    int*      csr   = (int*)p;      p = align256(p + (size_t)N_EDGES * sizeof(int));
    uint_t*   eb    = (uint_t*)p;   p = align256(p + (size_t)N_EDGES * sizeof(uint_t));
    int*      table = (int*)p;      p = align256(p + (size_t)NT * sizeof(int));
    int*      off   = (int*)p;      p = align256(p + (size_t)(N_NODES + 1) * sizeof(int));
    int*      bsumT = (int*)p;      p = align256(p + 256 * sizeof(int));
    int*      doneT = (int*)p;      p = align256(p + 256 * sizeof(int));
    short*    Whi   = (short*)p;    p = align256(p + (size_t)NW * sizeof(short));
    short*    Wlo   = (short*)p;    p = align256(p + (size_t)NW * sizeof(short));
    short*    WinHi = (short*)p;    p = align256(p + (size_t)WIN_N * sizeof(short));
    short*    WinLo = (short*)p;    p = align256(p + (size_t)WIN_N * sizeof(short));
    float*    sums  = (float*)p;
    float*    cntf  = (float*)(p + (size_t)N_GRAPHS * HID * sizeof(float));

    const int BLK = 256;
    const int nchunksT = (NT + SCHUNK - 1) / SCHUNK;   // 196

    k_prep<<<(NW + WIN_N) / BLK, BLK, 0, stream>>>(
        ggnn_w, gru_w_ih, gru_w_hh, W_in, Whi, Wlo, WinHi, WinLo, sums, doneT);

    k_cntin<<<CTOT, BLK, 0, stream>>>(
        edge_index, table, node_embed, WinHi, WinLo, b_in, h0);

    k_tscan1<<<nchunksT, SCHUNK, 0, stream>>>(table, bsumT, doneT);
    k_scatter<<<CNT_B, BLK, 0, stream>>>(edge_index, table, bsumT, eb);
    k_csr<<<NBUCK, BLK, 0, stream>>>(table, bsumT, eb, csr, off);

    // 5 fused layers, ping-pong h0/h1 (5 layers: final lands in h1)
    ushort_t* hin = h0;
    ushort_t* hout = h1;
    for (int l = 0; l < N_LAYERS; ++l) {
        k_layer<<<(N_NODES + 63) / 64, BLK, 0, stream>>>(
            off, csr, hin, hout, Whi + (size_t)l * WSTRIDE, Wlo + (size_t)l * WSTRIDE,
            gru_b_ih, gru_b_hh);
        ushort_t* t = hin; hin = hout; hout = t;
    }

    {
        int waves = (N_NODES + POOL_NPW - 1) / POOL_NPW;
        int threads = waves * 64;
        k_pool<<<(threads + BLK - 1) / BLK, BLK, 0, stream>>>(hin, batch, sums, cntf);
    }
    k_out<<<(N_GRAPHS * D_OUT + BLK - 1) / BLK, BLK, 0, stream>>>(sums, cntf, W_out, b_out, out);
}

// Round 18
// 398.353 us; speedup vs baseline: 1.2066x; 1.2066x over previous
//
#include <hip/hip_runtime.h>

#define N_NODES 100000
#define N_EDGES 1600000
#define D_IN 128
#define HID 64
#define N_LAYERS 5
#define D_OUT 32
#define N_GRAPHS 1000

// bucketed CSR build
#define BSHIFT 7                          // 128 nodes per bucket
#define NBUCK ((N_NODES + 127) >> BSHIFT) // 782
#define CNT_B 256                         // blocks in count/scatter passes
#define EPB (N_EDGES / CNT_B)             // 6250 edges per block slice
#define NT (NBUCK * CNT_B)                // table entries = 200192

typedef unsigned short ushort_t;
typedef unsigned int uint_t;
typedef __attribute__((ext_vector_type(8))) short short8;   // 8 bf16 (4 VGPRs)
typedef __attribute__((ext_vector_type(4))) float f32x4;    // MFMA accumulator

#define MFMA(a, b, c) __builtin_amdgcn_mfma_f32_16x16x32_bf16((a), (b), (c), 0, 0, 0)

// per-layer stride of the prepped GRU weight fragment arrays (in shorts)
#define WSTRIDE (24 * 2 * 64 * 8)
#define NW (N_LAYERS * WSTRIDE)          // 122880
#define WIN_N (4 * 4 * 64 * 8)           // W_in fragments per plane = 8192

#define IN_B ((N_NODES + 63) / 64)       // 1563 input-MFMA blocks
#define CTOT (CNT_B + IN_B)              // 1819 (coprime with 256)

__device__ __forceinline__ float fast_sigmoid(float x) {
    return __builtin_amdgcn_rcpf(1.0f + __expf(-x));
}
__device__ __forceinline__ float fast_tanh(float x) {
    return 1.0f - 2.0f * __builtin_amdgcn_rcpf(1.0f + __expf(2.0f * x));
}
// fp32 -> bf16 round-to-nearest-even
__device__ __forceinline__ ushort_t f2bf(float f) {
    uint_t u = __float_as_uint(f);
    return (ushort_t)((u + 0x7fffu + ((u >> 16) & 1u)) >> 16);
}
__device__ __forceinline__ float b2f(ushort_t u) {
    return __uint_as_float(((uint_t)u) << 16);
}

// ---------------------------------------------------------------------------
// Weight prep: GRU fragments (t < NW) and W_in fragments (t >= NW).
// Also zeroes sums/cnt and the tscan done-counter.
__global__ void k_prep(const float* __restrict__ ggnn_w,
                       const float* __restrict__ w_ih,
                       const float* __restrict__ w_hh,
                       const float* __restrict__ W_in,
                       short* __restrict__ Whi, short* __restrict__ Wlo,
                       short* __restrict__ WinHi, short* __restrict__ WinLo,
                       float* __restrict__ sums, int* __restrict__ done) {
    int t = blockIdx.x * blockDim.x + threadIdx.x;
    if (t == 0) *done = 0;
    if (t < N_GRAPHS * (HID + 1)) sums[t] = 0.0f;
    if (t < NW) {
        int i    = t & 7;
        int lane = (t >> 3) & 63;
        int s    = (t >> 9) & 1;
        int tt   = (t >> 10) % 24;
        int lay  = (t >> 10) / 24;
        int k    = s * 32 + (lane >> 4) * 8 + i;
        int col  = tt * 16 + (lane & 15);
        float val;
        if (col < 192) {
            const float* wl = ggnn_w + ((size_t)lay * HID + k) * HID;
            const float* wi = w_ih + (size_t)col * HID;
            float acc = 0.0f;
#pragma unroll 8
            for (int q = 0; q < HID; ++q) acc = fmaf(wl[q], wi[q], acc);
            val = acc;
        } else {
            val = w_hh[(size_t)(col - 192) * HID + k];
        }
        ushort_t h_ = f2bf(val);
        Whi[t] = (short)h_;
        Wlo[t] = (short)f2bf(val - b2f(h_));
        return;
    }
    int t2 = t - NW;
    if (t2 >= WIN_N) return;
    int i    = t2 & 7;
    int lane = (t2 >> 3) & 63;
    int jb   = (t2 >> 9) & 3;
    int s    = (t2 >> 11) & 3;
    int k    = s * 32 + (lane >> 4) * 8 + i;
    int col  = jb * 16 + (lane & 15);
    float val = W_in[(size_t)k * HID + col];
    ushort_t h_ = f2bf(val);
    WinHi[t2] = (short)h_;
    WinLo[t2] = (short)f2bf(val - b2f(h_));
}

// ---------------------------------------------------------------------------
// count + input-MFMA, role-interleaved via bijective permutation.
// Input A-side is single-rounded bf16 (error ~2^-9|x|, same order as the
// output's own bf16 rounding); weight-side keeps hi+lo compensation.
__global__ __launch_bounds__(256) void k_cntin(
        const int* __restrict__ ei, int* __restrict__ table,
        const float* __restrict__ ne,
        const short* __restrict__ WinHi, const short* __restrict__ WinLo,
        const float* __restrict__ b_in,
        ushort_t* __restrict__ h0) {
    __shared__ int hcnt[NBUCK];
    int tid = threadIdx.x;
    int swz = (int)(((long long)blockIdx.x * 256) % CTOT);

    if (swz < CNT_B) {
        int b = swz;
        for (int i = tid; i < NBUCK; i += 256) hcnt[i] = 0;
        __syncthreads();
        int e0 = b * EPB;
        for (int i = tid; i < EPB; i += 256)
            atomicAdd(&hcnt[ei[N_EDGES + e0 + i] >> BSHIFT], 1);
        __syncthreads();
        for (int i = tid; i < NBUCK; i += 256)
            table[i * CNT_B + b] = hcnt[i];
        return;
    }
    // ---- input linear via MFMA: x = ne @ W_in + b_in -> bf16 h0 ----
    int ib = swz - CNT_B;
    int wv = tid >> 6, l = tid & 63;
    int q = l >> 4, c = l & 15;
    int nodeBase = ib * 64 + wv * 16;
    int anode = nodeBase + c;
    int acl = (anode < N_NODES) ? anode : (N_NODES - 1);
    const float* erow = ne + (size_t)acl * D_IN;
    short8 Ah[4];
#pragma unroll
    for (int s = 0; s < 4; ++s) {
        float4 u0 = *(const float4*)(erow + s * 32 + q * 8);
        float4 u1 = *(const float4*)(erow + s * 32 + q * 8 + 4);
        Ah[s][0] = (short)f2bf(u0.x); Ah[s][1] = (short)f2bf(u0.y);
        Ah[s][2] = (short)f2bf(u0.z); Ah[s][3] = (short)f2bf(u0.w);
        Ah[s][4] = (short)f2bf(u1.x); Ah[s][5] = (short)f2bf(u1.y);
        Ah[s][6] = (short)f2bf(u1.z); Ah[s][7] = (short)f2bf(u1.w);
    }

    f32x4 acc[4];
    const f32x4 zero = {0.f, 0.f, 0.f, 0.f};
#pragma unroll
    for (int jb = 0; jb < 4; ++jb) acc[jb] = zero;
    const short8* BH = ((const short8*)WinHi) + l;
    const short8* BL = ((const short8*)WinLo) + l;
#pragma unroll
    for (int jb = 0; jb < 4; ++jb)
#pragma unroll
        for (int s = 0; s < 4; ++s) {
            short8 bh = BH[(s * 4 + jb) * 64];
            short8 bl = BL[(s * 4 + jb) * 64];
            acc[jb] = MFMA(Ah[s], bh, acc[jb]);
            acc[jb] = MFMA(Ah[s], bl, acc[jb]);
        }
#pragma unroll
    for (int jb = 0; jb < 4; ++jb) {
        int j = jb * 16 + c;
        float bb = b_in[j];
#pragma unroll
        for (int i = 0; i < 4; ++i) {
            int m = nodeBase + q * 4 + i;
            if (m < N_NODES)
                h0[(size_t)m * HID + j] = f2bf(acc[jb][i] + bb);
        }
    }
}

// ---------------------------------------------------------------------------
// Flat exclusive scan over NT entries; LAST BLOCK scans the chunk sums.
#define SCHUNK 1024
__global__ __launch_bounds__(1024) void k_tscan1(int* __restrict__ table,
                                                 int* __restrict__ bsum,
                                                 int* __restrict__ done) {
    __shared__ int buf[SCHUNK];
    __shared__ int lastFlag;
    int tid = threadIdx.x;
    int i = blockIdx.x * SCHUNK + tid;
    int v = (i < NT) ? table[i] : 0;
    buf[tid] = v;
    __syncthreads();
    for (int s = 1; s < SCHUNK; s <<= 1) {
        int a = (tid >= s) ? buf[tid - s] : 0;
        __syncthreads();
        buf[tid] += a;
        __syncthreads();
    }
    if (i < NT) table[i] = buf[tid] - v;    // exclusive within chunk
    if (tid == SCHUNK - 1) atomicExch(&bsum[blockIdx.x], buf[tid]);
    if (tid == 0) {
        __threadfence();
        lastFlag = (atomicAdd(done, 1) == (int)gridDim.x - 1) ? 1 : 0;
    }
    __syncthreads();
    if (!lastFlag) return;
    int nch = gridDim.x;
    int bv = (tid < nch) ? atomicAdd(&bsum[tid], 0) : 0;   // coherent read
    buf[tid] = bv;
    __syncthreads();
    for (int s = 1; s < SCHUNK; s <<= 1) {
        int a = (tid >= s) ? buf[tid - s] : 0;
        __syncthreads();
        buf[tid] += a;
        __syncthreads();
    }
    if (tid < nch) atomicExch(&bsum[tid], buf[tid] - bv);
}

// ---------------------------------------------------------------------------
// LDS counting-sort scatter; global eb entries packed: src | ((dst&127)<<17)
__global__ __launch_bounds__(256) void k_scatter(const int* __restrict__ ei,
                                                 const int* __restrict__ table,
                                                 const int* __restrict__ bsum,
                                                 uint_t* __restrict__ eb) {
    __shared__ uint2 stage[EPB];        // 50,000 B
    __shared__ int hoff[NBUCK];
    __shared__ int hslot[NBUCK];
    __shared__ int sbuf[256];
    int b = blockIdx.x, tid = threadIdx.x;
    for (int i = tid; i < NBUCK; i += 256) { hoff[i] = 0; hslot[i] = 0; }
    __syncthreads();
    int e0 = b * EPB;
    for (int i = tid; i < EPB; i += 256)
        atomicAdd(&hoff[ei[N_EDGES + e0 + i] >> BSHIFT], 1);
    __syncthreads();
    int base = tid * 4;
    int c0 = (base + 0 < NBUCK) ? hoff[base + 0] : 0;
    int c1 = (base + 1 < NBUCK) ? hoff[base + 1] : 0;
    int c2 = (base + 2 < NBUCK) ? hoff[base + 2] : 0;
    int c3 = (base + 3 < NBUCK) ? hoff[base + 3] : 0;
    int tot = c0 + c1 + c2 + c3;
    sbuf[tid] = tot;
    __syncthreads();
    for (int s = 1; s < 256; s <<= 1) {
        int a = (tid >= s) ? sbuf[tid - s] : 0;
        __syncthreads();
        sbuf[tid] += a;
        __syncthreads();
    }
    int mybase = sbuf[tid] - tot;
    __syncthreads();
    if (base + 0 < NBUCK) hoff[base + 0] = mybase;
    if (base + 1 < NBUCK) hoff[base + 1] = mybase + c0;
    if (base + 2 < NBUCK) hoff[base + 2] = mybase + c0 + c1;
    if (base + 3 < NBUCK) hoff[base + 3] = mybase + c0 + c1 + c2;
    __syncthreads();
    for (int i = tid; i < EPB; i += 256) {
        int s = ei[e0 + i];
        int d = ei[N_EDGES + e0 + i];
        int bk = d >> BSHIFT;
        int pos = hoff[bk] + atomicAdd(&hslot[bk], 1);
        uint2 v; v.x = (uint_t)s; v.y = (uint_t)d;
        stage[pos] = v;
    }
    __syncthreads();
    for (int p = tid; p < EPB; p += 256) {
        uint2 e = stage[p];
        int bk = (int)e.y >> BSHIFT;
        int gidx = bk * CNT_B + b;
        int gbase = table[gidx] + bsum[gidx >> 10];
        eb[gbase + (p - hoff[bk])] = e.x | ((e.y & 127u) << 17);
    }
}

// ---------------------------------------------------------------------------
// per-bucket local CSR build (packed eb: src = e&0x1FFFF, dst-local = e>>17)
__global__ __launch_bounds__(256) void k_csr(const int* __restrict__ table,
                                             const int* __restrict__ bsum,
                                             const uint_t* __restrict__ eb,
                                             int* __restrict__ csr,
                                             int* __restrict__ off) {
    __shared__ int cnt[128];
    __shared__ int slot[128];
    int b = blockIdx.x, tid = threadIdx.x;
    int nodeBase = b << BSHIFT;
    int nn = min(128, N_NODES - nodeBase);
    int i0 = b * CNT_B;
    int beg = table[i0] + bsum[i0 >> 10];
    int end;
    if (b == NBUCK - 1) end = N_EDGES;
    else {
        int i1 = (b + 1) * CNT_B;
        end = table[i1] + bsum[i1 >> 10];
    }

    if (tid < 128) { cnt[tid] = 0; slot[tid] = 0; }
    __syncthreads();
    for (int i = beg + tid; i < end; i += 256)
        atomicAdd(&cnt[(eb[i] >> 17) & 127u], 1);
    __syncthreads();
    int orig = (tid < 128) ? cnt[tid] : 0;
    for (int s = 1; s < 128; s <<= 1) {
        int a = (tid >= s && tid < 128) ? cnt[tid - s] : 0;
        __syncthreads();
        if (tid < 128) cnt[tid] += a;
        __syncthreads();
    }
    int start = 0;
    if (tid < 128) start = beg + cnt[tid] - orig;
    __syncthreads();
    if (tid < 128) {
        cnt[tid] = start;
        if (tid < nn) off[nodeBase + tid] = start;
    }
    if (b == NBUCK - 1 && tid == 0) off[N_NODES] = N_EDGES;
    __syncthreads();
    for (int i = beg + tid; i < end; i += 256) {
        uint_t e = eb[i];
        int ln = (e >> 17) & 127u;
        int p = cnt[ln] + atomicAdd(&slot[ln], 1);
        csr[p] = (int)(e & 0x1FFFFu);
    }
}

// ---------------------------------------------------------------------------
// CSR gather: one wave per node, 8 neighbor rows in flight, bf16 out.
__global__ __launch_bounds__(256) void k_gather(const int* __restrict__ off,
                                                const int* __restrict__ csr,
                                                const ushort_t* __restrict__ hb,
                                                ushort_t* __restrict__ aggb) {
    int t = blockIdx.x * blockDim.x + threadIdx.x;
    int n = t >> 6;
    int lane = t & 63;
    int q = lane >> 3, c = lane & 7;
    int beg = off[n], end = off[n + 1];
    float a[8];
#pragma unroll
    for (int x = 0; x < 8; ++x) a[x] = 0.f;
#pragma unroll 2
    for (int i = beg; i < end; i += 8) {
        int idx = i + q;
        int sidx = csr[min(idx, end - 1)];
        float msk = (idx < end) ? 1.0f : 0.0f;
        uint4 v = *(const uint4*)(hb + (size_t)sidx * HID + c * 8);
        a[0] = fmaf(msk, __uint_as_float(v.x << 16), a[0]);
        a[1] = fmaf(msk, __uint_as_float(v.x & 0xffff0000u), a[1]);
        a[2] = fmaf(msk, __uint_as_float(v.y << 16), a[2]);
        a[3] = fmaf(msk, __uint_as_float(v.y & 0xffff0000u), a[3]);
        a[4] = fmaf(msk, __uint_as_float(v.z << 16), a[4]);
        a[5] = fmaf(msk, __uint_as_float(v.z & 0xffff0000u), a[5]);
        a[6] = fmaf(msk, __uint_as_float(v.w << 16), a[6]);
        a[7] = fmaf(msk, __uint_as_float(v.w & 0xffff0000u), a[7]);
    }
#pragma unroll
    for (int x = 0; x < 8; ++x) {
        a[x] += __shfl_xor(a[x], 8);
        a[x] += __shfl_xor(a[x], 16);
        a[x] += __shfl_xor(a[x], 32);
    }
    if (q == 0) {
        uint4 o;
        o.x = (uint_t)f2bf(a[0]) | ((uint_t)f2bf(a[1]) << 16);
        o.y = (uint_t)f2bf(a[2]) | ((uint_t)f2bf(a[3]) << 16);
        o.z = (uint_t)f2bf(a[4]) | ((uint_t)f2bf(a[5]) << 16);
        o.w = (uint_t)f2bf(a[6]) | ((uint_t)f2bf(a[7]) << 16);
        *(uint4*)(aggb + (size_t)n * HID + c * 8) = o;
    }
}

// ---------------------------------------------------------------------------
// MFMA GRU, sequential jb quadrants. r/z gates use single-rounded (hi-only)
// weights; tanh (n) path keeps hi+lo. 64 MFMAs; weights direct from L2.
__global__ __launch_bounds__(256) void k_gru(const ushort_t* __restrict__ aggb,
                                             ushort_t* __restrict__ hbhi,
                                             const short* __restrict__ Whi,
                                             const short* __restrict__ Wlo,
                                             const float* __restrict__ b_ih,
                                             const float* __restrict__ b_hh) {
    int tid = threadIdx.x;
    int wv = tid >> 6, l = tid & 63;
    int q = l >> 4, c = l & 15;
    int nodeBase = blockIdx.x * 64 + wv * 16;

    int anode = nodeBase + c;
    int acl = (anode < N_NODES) ? anode : (N_NODES - 1);
    const ushort_t* arow = aggb + (size_t)acl * HID;
    const ushort_t* hrow = hbhi + (size_t)acl * HID;
    short8 Ag[2], Ah[2];
    Ag[0] = *(const short8*)(arow + q * 8);
    Ag[1] = *(const short8*)(arow + 32 + q * 8);
    Ah[0] = *(const short8*)(hrow + q * 8);
    Ah[1] = *(const short8*)(hrow + 32 + q * 8);

    const short8* BH = ((const short8*)Whi) + l;
    const short8* BL = ((const short8*)Wlo) + l;
    const f32x4 zero = {0.f, 0.f, 0.f, 0.f};

#pragma unroll
    for (int jb = 0; jb < 4; ++jb) {
        f32x4 acc6[6];
#pragma unroll
        for (int g = 0; g < 6; ++g) acc6[g] = zero;
#pragma unroll
        for (int g = 0; g < 6; ++g) {
            int t = g * 4 + jb;
            short8 b0h = BH[(t * 2 + 0) * 64];
            short8 b1h = BH[(t * 2 + 1) * 64];
            short8 a0 = (g < 3) ? Ag[0] : Ah[0];
            short8 a1 = (g < 3) ? Ag[1] : Ah[1];
            acc6[g] = MFMA(a0, b0h, acc6[g]);
            acc6[g] = MFMA(a1, b1h, acc6[g]);
            if (g == 2 || g == 5) {          // tanh path keeps lo-residual
                short8 b0l = BL[(t * 2 + 0) * 64];
                short8 b1l = BL[(t * 2 + 1) * 64];
                acc6[g] = MFMA(a0, b0l, acc6[g]);
                acc6[g] = MFMA(a1, b1l, acc6[g]);
            }
        }
        int j = jb * 16 + c;
        float br  = b_ih[j] + b_hh[j];
        float bz  = b_ih[64 + j] + b_hh[64 + j];
        float bin = b_ih[128 + j];
        float bhn = b_hh[128 + j];
#pragma unroll
        for (int i = 0; i < 4; ++i) {
            int m = nodeBase + q * 4 + i;
            if (m < N_NODES) {
                float rr = fast_sigmoid(acc6[0][i] + acc6[3][i] + br);
                float zz = fast_sigmoid(acc6[1][i] + acc6[4][i] + bz);
                float nv = fast_tanh((acc6[2][i] + bin) + rr * (acc6[5][i] + bhn));
                size_t idx = (size_t)m * HID + j;
                float hold = b2f(hbhi[idx]);
                hbhi[idx] = f2bf((1.0f - zz) * nv + zz * hold);
            }
        }
    }
}

// ---------------------------------------------------------------------------
#define POOL_NPW 32
__global__ void k_pool(const ushort_t* __restrict__ hb,
                       const int* __restrict__ batch,
                       float* __restrict__ sums,
                       float* __restrict__ cntf) {
    int wid = (blockIdx.x * blockDim.x + threadIdx.x) >> 6;
    int j = threadIdx.x & 63;
    int base = wid * POOL_NPW;
    if (base >= N_NODES) return;
    int end = base + POOL_NPW;
    if (end > N_NODES) end = N_NODES;
    float acc = 0.f, c = 0.f;
    int curg = batch[base];
    for (int n = base; n < end; ++n) {
        int g = batch[n];
        if (g != curg) {
            atomicAdd(&sums[(size_t)curg * HID + j], acc);
            if (j == 0) atomicAdd(&cntf[curg], c);
            acc = 0.f; c = 0.f; curg = g;
        }
        acc += b2f(hb[(size_t)n * HID + j]);
        c += 1.f;
    }
    atomicAdd(&sums[(size_t)curg * HID + j], acc);
    if (j == 0) atomicAdd(&cntf[curg], c);
}

__global__ void k_out(const float* __restrict__ sums,
                      const float* __restrict__ cntf,
                      const float* __restrict__ W_out,
                      const float* __restrict__ b_out,
                      float* __restrict__ out) {
    int t = blockIdx.x * blockDim.x + threadIdx.x;
    if (t >= N_GRAPHS * D_OUT) return;
    int g = t / D_OUT, o = t % D_OUT;
    float inv_c = __builtin_amdgcn_rcpf(fmaxf(cntf[g], 1.0f));
    float acc = 0.0f;
#pragma unroll
    for (int k = 0; k < HID; ++k)
        acc = fmaf(sums[g * HID + k], W_out[k * D_OUT + o], acc);
    out[t] = acc * inv_c + b_out[o];
}

// ---------------------------------------------------------------------------
static inline char* align256(char* p) {
    return (char*)(((uintptr_t)p + 255) & ~(uintptr_t)255);
}

extern "C" void kernel_launch(void* const* d_in, const int* in_sizes, int n_in,
                              void* d_out, int out_size, void* d_ws, size_t ws_size,
                              hipStream_t stream) {
    const float* node_embed = (const float*)d_in[0];
    const int*   edge_index = (const int*)  d_in[1];
    const int*   batch      = (const int*)  d_in[2];
    const float* W_in       = (const float*)d_in[3];
    const float* b_in       = (const float*)d_in[4];
    const float* ggnn_w     = (const float*)d_in[5];
    const float* gru_w_ih   = (const float*)d_in[6];
    const float* gru_w_hh   = (const float*)d_in[7];
    const float* gru_b_ih   = (const float*)d_in[8];
    const float* gru_b_hh   = (const float*)d_in[9];
    const float* W_out      = (const float*)d_in[10];
    const float* b_out      = (const float*)d_in[11];
    float* out = (float*)d_out;

    char* p = (char*)d_ws;
    ushort_t* hbhi  = (ushort_t*)p; p = align256(p + (size_t)N_NODES * HID * sizeof(ushort_t));
    ushort_t* aggb  = (ushort_t*)p; p = align256(p + (size_t)N_NODES * HID * sizeof(ushort_t));
    int*      csr   = (int*)p;      p = align256(p + (size_t)N_EDGES * sizeof(int));
    uint_t*   eb    = (uint_t*)p;   p = align256(p + (size_t)N_EDGES * sizeof(uint_t));
    int*      table = (int*)p;      p = align256(p + (size_t)NT * sizeof(int));
    int*      off   = (int*)p;      p = align256(p + (size_t)(N_NODES + 1) * sizeof(int));
    int*      bsumT = (int*)p;      p = align256(p + 256 * sizeof(int));
    int*      doneT = (int*)p;      p = align256(p + 256 * sizeof(int));
    short*    Whi   = (short*)p;    p = align256(p + (size_t)NW * sizeof(short));
    short*    Wlo   = (short*)p;    p = align256(p + (size_t)NW * sizeof(short));
    short*    WinHi = (short*)p;    p = align256(p + (size_t)WIN_N * sizeof(short));
    short*    WinLo = (short*)p;    p = align256(p + (size_t)WIN_N * sizeof(short));
    float*    sums  = (float*)p;
    float*    cntf  = (float*)(p + (size_t)N_GRAPHS * HID * sizeof(float));

    const int BLK = 256;
    const int nchunksT = (NT + SCHUNK - 1) / SCHUNK;   // 196

    k_prep<<<(NW + WIN_N) / BLK, BLK, 0, stream>>>(
        ggnn_w, gru_w_ih, gru_w_hh, W_in, Whi, Wlo, WinHi, WinLo, sums, doneT);

    k_cntin<<<CTOT, BLK, 0, stream>>>(
        edge_index, table, node_embed, WinHi, WinLo, b_in, hbhi);

    k_tscan1<<<nchunksT, SCHUNK, 0, stream>>>(table, bsumT, doneT);
    k_scatter<<<CNT_B, BLK, 0, stream>>>(edge_index, table, bsumT, eb);
    k_csr<<<NBUCK, BLK, 0, stream>>>(table, bsumT, eb, csr, off);

    for (int l = 0; l < N_LAYERS; ++l) {
        k_gather<<<N_NODES * 64 / BLK, BLK, 0, stream>>>(off, csr, hbhi, aggb);
        k_gru<<<(N_NODES + 63) / 64, BLK, 0, stream>>>(
            aggb, hbhi, Whi + (size_t)l * WSTRIDE, Wlo + (size_t)l * WSTRIDE,
            gru_b_ih, gru_b_hh);
    }

    {
        int waves = (N_NODES + POOL_NPW - 1) / POOL_NPW;
        int threads = waves * 64;
        k_pool<<<(threads + BLK - 1) / BLK, BLK, 0, stream>>>(hbhi, batch, sums, cntf);
    }
    k_out<<<(N_GRAPHS * D_OUT + BLK - 1) / BLK, BLK, 0, stream>>>(sums, cntf, W_out, b_out, out);
}